// Round 10
// baseline (139.487 us; speedup 1.0000x reference)
//
#include <hip/hip_runtime.h>
#include <math.h>

// InterContactLoss on MI355X — round 10: two-pass MFMA, row-min only; fence-free.
//
// r9 evidence: (a) physical-VGPR banks improved mindist (<41.7us, out of top-5);
// (b) reduce_finalize = 41.76us @ 1.2% VALUBusy -> the per-block __threadfence
// (L2 writeback x559 blocks) is the stall. Fixes:
//  - mindist runs BOTH directions as row-min MFMA passes (pass2 swaps operands:
//    A=object rows, B=human cols via prepped 216-tile fragments, pad cols
//    bb=1e36). Col-trees, LDS atomics, cmin, syncthreads: all deleted.
//    Per dual-tile REDUCE = 16 tied v_min3 bank-fold. Direct stores only.
//  - reduce (atomicAdd only) and finalize (<<<1,1>>>) are separate kernels;
//    kernel boundary provides visibility -> no fence, no counter, no spin.
// Harness floor: 256MB ws-poison fill (~43us @ 79% HBM) + launch gaps.

#define BT 16
#define VH 6890
#define VO 2048
#define NH (BT * VH)    // 110240
#define NO (BT * VO)    // 32768
#define RBLK1 54        // pass1 row-blocks/prob: ceil(6890/128)
#define RBLK2 16        // pass2 row-blocks/prob: 2048/128
#define NT1 64          // pass1 col tiles (2048/32)
#define NT2 216         // pass2 col tiles (6912/32, cols padded)
#define NPROB 32        // 16 bt x {pred,gt}
#define NBLK1 (NPROB * RBLK1)   // 1728
#define NBLK2 (NPROB * RBLK2)   // 512

typedef __attribute__((ext_vector_type(8))) short          short8;
typedef __attribute__((ext_vector_type(8))) unsigned short ushort8;

__device__ __forceinline__ unsigned short bf16_rne(float f) {
    const unsigned int u = __float_as_uint(f);
    return (unsigned short)((u + 0x7FFFu + ((u >> 16) & 1u)) >> 16);
}
__device__ __forceinline__ float bf16_tof(unsigned short h) {
    return __uint_as_float(((unsigned int)h) << 16);
}

#define CLOB_B0 "v40","v41","v42","v43","v44","v45","v46","v47", \
                "v48","v49","v50","v51","v52","v53","v54","v55", \
                "v56","v57","v58","v59","v60","v61","v62","v63", \
                "v64","v65","v66","v67","v68","v69","v70","v71"
#define CLOB_B1 "v72","v73","v74","v75","v76","v77","v78","v79", \
                "v80","v81","v82","v83","v84","v85","v86","v87", \
                "v88","v89","v90","v91","v92","v93","v94","v95", \
                "v96","v97","v98","v99","v100","v101","v102","v103"

#define MFMA_B0(b0, b1) \
    asm volatile("v_mfma_f32_32x32x16_bf16 v[40:55], %0, %1, 0\n\t" \
                 "v_mfma_f32_32x32x16_bf16 v[56:71], %0, %2, 0" \
                 :: "v"(a8), "v"(b0), "v"(b1) : CLOB_B0)
#define MFMA_B1(b0, b1) \
    asm volatile("v_mfma_f32_32x32x16_bf16 v[72:87], %0, %1, 0\n\t" \
                 "v_mfma_f32_32x32x16_bf16 v[88:103], %0, %2, 0" \
                 :: "v"(a8), "v"(b0), "v"(b1) : CLOB_B1)

// Fold one bank (2 tiles) into rm: 16 tied min3, nothing else.
#define RED_B0() \
    asm volatile( \
        "v_min3_f32 %0, %0, v40, v56\n\t"  "v_min3_f32 %1, %1, v41, v57\n\t" \
        "v_min3_f32 %2, %2, v42, v58\n\t"  "v_min3_f32 %3, %3, v43, v59\n\t" \
        "v_min3_f32 %4, %4, v44, v60\n\t"  "v_min3_f32 %5, %5, v45, v61\n\t" \
        "v_min3_f32 %6, %6, v46, v62\n\t"  "v_min3_f32 %7, %7, v47, v63\n\t" \
        "v_min3_f32 %8, %8, v48, v64\n\t"  "v_min3_f32 %9, %9, v49, v65\n\t" \
        "v_min3_f32 %10, %10, v50, v66\n\t" "v_min3_f32 %11, %11, v51, v67\n\t" \
        "v_min3_f32 %12, %12, v52, v68\n\t" "v_min3_f32 %13, %13, v53, v69\n\t" \
        "v_min3_f32 %14, %14, v54, v70\n\t" "v_min3_f32 %15, %15, v55, v71" \
        : "+v"(rm[0]), "+v"(rm[1]), "+v"(rm[2]),  "+v"(rm[3]), \
          "+v"(rm[4]), "+v"(rm[5]), "+v"(rm[6]),  "+v"(rm[7]), \
          "+v"(rm[8]), "+v"(rm[9]), "+v"(rm[10]), "+v"(rm[11]), \
          "+v"(rm[12]),"+v"(rm[13]),"+v"(rm[14]), "+v"(rm[15]))
#define RED_B1() \
    asm volatile( \
        "v_min3_f32 %0, %0, v72, v88\n\t"  "v_min3_f32 %1, %1, v73, v89\n\t" \
        "v_min3_f32 %2, %2, v74, v90\n\t"  "v_min3_f32 %3, %3, v75, v91\n\t" \
        "v_min3_f32 %4, %4, v76, v92\n\t"  "v_min3_f32 %5, %5, v77, v93\n\t" \
        "v_min3_f32 %6, %6, v78, v94\n\t"  "v_min3_f32 %7, %7, v79, v95\n\t" \
        "v_min3_f32 %8, %8, v80, v96\n\t"  "v_min3_f32 %9, %9, v81, v97\n\t" \
        "v_min3_f32 %10, %10, v82, v98\n\t" "v_min3_f32 %11, %11, v83, v99\n\t" \
        "v_min3_f32 %12, %12, v84, v100\n\t" "v_min3_f32 %13, %13, v85, v101\n\t" \
        "v_min3_f32 %14, %14, v86, v102\n\t" "v_min3_f32 %15, %15, v87, v103" \
        : "+v"(rm[0]), "+v"(rm[1]), "+v"(rm[2]),  "+v"(rm[3]), \
          "+v"(rm[4]), "+v"(rm[5]), "+v"(rm[6]),  "+v"(rm[7]), \
          "+v"(rm[8]), "+v"(rm[9]), "+v"(rm[10]), "+v"(rm[11]), \
          "+v"(rm[12]),"+v"(rm[13]),"+v"(rm[14]), "+v"(rm[15]))

// ---- prep: object B-frags (64 tiles) + human B-frags (216 tiles) + acc zero ----
__global__ __launch_bounds__(256)
void prep_kernel(const float* __restrict__ hv,  const float* __restrict__ ov,
                 const float* __restrict__ ghv, const float* __restrict__ gov,
                 unsigned short* __restrict__ BfragO, unsigned short* __restrict__ BfragH,
                 unsigned int* __restrict__ acc)
{
    const int t = blockIdx.x * 256 + threadIdx.x;   // 286720 total
    if (t < 16) acc[t] = 0u;

    const unsigned short one = 0x3F80;
    if (t < 65536) {                                // object frags: [pg][bt][col<2048]
        const int col = t & 2047;
        const int bt  = (t >> 11) & 15;
        const int pg  = t >> 15;
        const float* B = (pg ? gov : ov) + ((size_t)bt * VO + col) * 3;
        const float bx = B[0], by = B[1], bz = B[2];
        const float m2x = -2.f * bx, m2y = -2.f * by, m2z = -2.f * bz;
        const float bb  = fmaf(bx, bx, fmaf(by, by, bz * bz));
        const unsigned short hx = bf16_rne(m2x), hy = bf16_rne(m2y), hz = bf16_rne(m2z);
        const unsigned short lx = bf16_rne(m2x - bf16_tof(hx));
        const unsigned short ly = bf16_rne(m2y - bf16_tof(hy));
        const unsigned short lz = bf16_rne(m2z - bf16_tof(hz));
        const unsigned short bh = bf16_rne(bb);
        const unsigned short bl = bf16_rne(bb - bf16_tof(bh));
        const int prob = pg * 16 + bt;
        unsigned short* d0 = BfragO +
            ((size_t)((prob * NT1 + (col >> 5)) * 64 + (col & 31))) * 8;
        const ushort8 w0 = {hx, hy, hz, hx, hy, hz, one, one};   // k0..7
        const ushort8 w1 = {lx, ly, lz, lx, ly, lz, bh, bl};     // k8..15
        *(ushort8*)d0         = w0;
        *(ushort8*)(d0 + 256) = w1;
    } else {                                        // human frags: [prob][col<6912]
        const int t2   = t - 65536;                 // 221184 = 32 * 6912
        const int col  = t2 % 6912;
        const int prob = t2 / 6912;
        const int pg = prob >> 4, bt = prob & 15;
        ushort8 w0, w1;
        if (col < VH) {
            const float* B = (pg ? ghv : hv) + ((size_t)bt * VH + col) * 3;
            const float bx = B[0], by = B[1], bz = B[2];
            const float m2x = -2.f * bx, m2y = -2.f * by, m2z = -2.f * bz;
            const float bb  = fmaf(bx, bx, fmaf(by, by, bz * bz));
            const unsigned short hx = bf16_rne(m2x), hy = bf16_rne(m2y), hz = bf16_rne(m2z);
            const unsigned short lx = bf16_rne(m2x - bf16_tof(hx));
            const unsigned short ly = bf16_rne(m2y - bf16_tof(hy));
            const unsigned short lz = bf16_rne(m2z - bf16_tof(hz));
            const unsigned short bh = bf16_rne(bb);
            const unsigned short bl = bf16_rne(bb - bf16_tof(bh));
            w0 = (ushort8){hx, hy, hz, hx, hy, hz, one, one};
            w1 = (ushort8){lx, ly, lz, lx, ly, lz, bh, bl};
        } else {
            // pad col: b=0, bb=1e36 -> d2 = aa + 1e36, never the min
            const unsigned short big = bf16_rne(1.0e36f);
            w0 = (ushort8){0, 0, 0, 0, 0, 0, one, one};
            w1 = (ushort8){0, 0, 0, 0, 0, 0, big, 0};
        }
        unsigned short* d0 = BfragH +
            ((size_t)((prob * NT2 + (col >> 5)) * 64 + (col & 31))) * 8;
        *(ushort8*)d0         = w0;
        *(ushort8*)(d0 + 256) = w1;
    }
}

// ---- mindist: 2240 blocks; pass1 = human rows x object cols, pass2 swapped ----
__global__ __launch_bounds__(256)
void mindist_mfma(const float* __restrict__ hv,  const float* __restrict__ ov,
                  const float* __restrict__ ghv, const float* __restrict__ gov,
                  const unsigned short* __restrict__ BfragO,
                  const unsigned short* __restrict__ BfragH,
                  float* __restrict__ rowm,      // [prob][VH]   human-side min d2
                  float* __restrict__ objm)      // [prob][2048] object-side min d2
{
    const int tid  = threadIdx.x;
    const int lane = tid & 63;
    const int wave = tid >> 6;
    const int b    = blockIdx.x;

    const float* A;
    const short8* bls;
    float* out;
    int pairs, nA, row0;

    if (b < NBLK1) {
        const int prob = b / RBLK1, rblk = b - prob * RBLK1;
        const int pg = prob >> 4, bt = prob & 15;
        A    = (pg ? ghv : hv) + (size_t)bt * VH * 3;
        bls  = (const short8*)BfragO + (size_t)prob * (NT1 * 64);
        out  = rowm + (size_t)prob * VH;
        pairs = NT1 / 2; nA = VH; row0 = rblk * 128 + wave * 32;
    } else {
        const int b2 = b - NBLK1;
        const int prob = b2 >> 4, rblk = b2 & 15;
        const int pg = prob >> 4, bt = prob & 15;
        A    = (pg ? gov : ov) + (size_t)bt * VO * 3;
        bls  = (const short8*)BfragH + (size_t)prob * (NT2 * 64);
        out  = objm + (size_t)prob * 2048;
        pairs = NT2 / 2; nA = VO; row0 = rblk * 128 + wave * 32;
    }

    // ---- A fragment: 32 rows/wave, split-bf16; pad rows -> (1e4,0,0) ----
    const int r = row0 + (lane & 31);
    float x, y, z;
    if (r < nA) { x = A[3*r]; y = A[3*r+1]; z = A[3*r+2]; }
    else        { x = 1.0e4f; y = 0.f;      z = 0.f; }
    const float aa = fmaf(x, x, fmaf(y, y, z * z));
    const unsigned short ahx = bf16_rne(x), ahy = bf16_rne(y), ahz = bf16_rne(z);
    const unsigned short alx = bf16_rne(x - bf16_tof(ahx));
    const unsigned short aly = bf16_rne(y - bf16_tof(ahy));
    const unsigned short alz = bf16_rne(z - bf16_tof(ahz));
    const unsigned short aah = bf16_rne(aa);
    const unsigned short aal = bf16_rne(aa - bf16_tof(aah));
    const int g = lane >> 5;
    ushort8 a8u;
    a8u[0] = ahx; a8u[1] = ahy; a8u[2] = ahz;
    a8u[3] = alx; a8u[4] = aly; a8u[5] = alz;
    a8u[6] = g ? (unsigned short)0x3F80 : aah;
    a8u[7] = g ? (unsigned short)0x3F80 : aal;
    const short8 a8 = (short8)a8u;

#define LD(jt) bls[(jt) * 64 + lane]
    float rm[16];
#pragma unroll
    for (int i = 0; i < 16; ++i) rm[i] = 3.0e38f;

    // banked pipeline: MFMA(pair p) ; RED(pair p-1)
    short8 bE0 = LD(0), bE1 = LD(1);
    MFMA_B0(bE0, bE1);
    short8 bO0 = LD(2), bO1 = LD(3);

    for (int s = 1; s < pairs - 1; s += 2) {
        bE0 = LD(2*s + 2); bE1 = LD(2*s + 3);
        MFMA_B1(bO0, bO1);
        RED_B0();
        bO0 = LD(2*s + 4); bO1 = LD(2*s + 5);
        MFMA_B0(bE0, bE1);
        RED_B1();
    }
    MFMA_B1(bO0, bO1);                    // last pair
    RED_B0();
    asm volatile("s_nop 7\n\ts_nop 7");   // spacing for final bank1 read
    RED_B1();
#undef LD

    // ---- row-min butterfly across the 32 col-lanes, then direct store ----
#pragma unroll
    for (int i = 0; i < 16; ++i) {
        float v = rm[i];
        v = fminf(v, __shfl_xor(v, 1));
        v = fminf(v, __shfl_xor(v, 2));
        v = fminf(v, __shfl_xor(v, 4));
        v = fminf(v, __shfl_xor(v, 8));
        v = fminf(v, __shfl_xor(v, 16));
        rm[i] = v;
    }
    if ((lane & 31) == 0) {               // lanes 0 and 32 hold 16 rows each
#pragma unroll
        for (int i = 0; i < 16; ++i) {
            const int rr = row0 + (i & 3) + 8 * (i >> 2) + 4 * g;
            if (rr < nA) out[rr] = fmaxf(rm[i], 0.f);
        }
    }
}

// ---- reduce: per-element loss -> block sums -> device atomicAdd (NO fence) ----
#define NBLK_H 431   // ceil(110240/256)
#define NBLK_O 128   // 32768/256
#define NBLKR  (NBLK_H + NBLK_O)

__global__ __launch_bounds__(256)
void reduce_kernel(const float* __restrict__ rowm, const float* __restrict__ objm,
                   float* __restrict__ acc)
{
    const int b = blockIdx.x;
    float p2 = 3.0e38f, g2 = 3.0e38f;
    float* a4;
    bool valid;

    if (b < NBLK_H) {
        a4 = acc;
        const int i = b * 256 + threadIdx.x;
        valid = (i < NH);
        if (valid) {
            const int bt = i / VH;
            const int r  = i - bt * VH;
            p2 = rowm[(size_t)bt * VH + r];
            g2 = rowm[(size_t)(16 + bt) * VH + r];
        }
    } else {
        a4 = acc + 4;
        const int i = (b - NBLK_H) * 256 + threadIdx.x;
        valid = true;
        const int bt = i >> 11;
        const int j  = i & 2047;
        p2 = objm[(size_t)bt * 2048 + j];
        g2 = objm[(size_t)(16 + bt) * 2048 + j];
    }

    float t = 0.f, sp = 0.f, sn = 0.f, sh = 0.f;
    if (valid) {
        const float d  = sqrtf(p2);
        const float dg = sqrtf(g2);
        const float tt = (dg < 0.2f) ? 1.f : 0.f;

        const float z = (0.2f - d) * 100.0f;           // (DIST_THR - d)/ALPHA
        float p = 1.0f / (1.0f + expf(-z));
        p = fminf(fmaxf(p, 1e-6f), 1.0f - 1e-6f);
        const float bce = (tt > 0.5f) ? -logf(p) : -logf(1.0f - p);

        const float over = fmaxf(d - 0.1f, 0.0f);      // d - CONTACT_TGT
        const float hub  = (over < 0.01f) ? (0.5f * over * over) / 0.01f
                                          : (over - 0.5f * 0.01f);
        t  = tt;
        sp = tt * bce;
        sn = (1.0f - tt) * bce;
        sh = tt * hub;
    }
    for (int off = 32; off > 0; off >>= 1) {
        t  += __shfl_down(t,  off);
        sp += __shfl_down(sp, off);
        sn += __shfl_down(sn, off);
        sh += __shfl_down(sh, off);
    }
    __shared__ float wsum[4][4];
    const int wid = threadIdx.x >> 6, lane = threadIdx.x & 63;
    if (lane == 0) {
        wsum[wid][0] = t; wsum[wid][1] = sp; wsum[wid][2] = sn; wsum[wid][3] = sh;
    }
    __syncthreads();
    if (threadIdx.x == 0) {
        float s0 = 0, s1 = 0, s2 = 0, s3 = 0;
        for (int w = 0; w < 4; ++w) {
            s0 += wsum[w][0]; s1 += wsum[w][1]; s2 += wsum[w][2]; s3 += wsum[w][3];
        }
        atomicAdd(&a4[0], s0);
        atomicAdd(&a4[1], s1);
        atomicAdd(&a4[2], s2);
        atomicAdd(&a4[3], s3);
    }
}

// ---- finalize: one thread; previous kernel's atomics visible at boundary ----
__global__ void finalize_kernel(const float* __restrict__ acc, float* __restrict__ outp)
{
    const float Ph = acc[0], SpH = acc[1], SnH = acc[2], ShH = acc[3];
    const float Po = acc[4], SpO = acc[5], SnO = acc[6], ShO = acc[7];
    const float Nh = (float)NH, No = (float)NO;

    const float pwH = ((Nh - Ph) + 1e-6f) / (Ph + 1e-6f);
    const float pwO = ((No - Po) + 1e-6f) / (Po + 1e-6f);
    const float bceH = (pwH * SpH + SnH) / Nh;
    const float bceO = (pwO * SpO + SnO) / No;
    const float Lbce = 0.5f * (bceH + bceO);

    const float LdH = (Ph > 0.f) ? ShH / fmaxf(Ph, 1.f) : 0.f;
    const float LdO = (Po > 0.f) ? ShO / fmaxf(Po, 1.f) : 0.f;

    outp[0] = 0.5f * Lbce + (LdH + LdO);
}

extern "C" void kernel_launch(void* const* d_in, const int* in_sizes, int n_in,
                              void* d_out, int out_size, void* d_ws, size_t ws_size,
                              hipStream_t stream)
{
    const float* hv  = (const float*)d_in[0];
    const float* ov  = (const float*)d_in[1];
    const float* ghv = (const float*)d_in[2];
    const float* gov = (const float*)d_in[3];

    unsigned short* BfragO = (unsigned short*)d_ws;                    // 32*64*64*8  = 2MB
    unsigned short* BfragH = BfragO + (size_t)NPROB * NT1 * 64 * 8;    // 32*216*64*8 ~ 6.75MB
    float*          rowm   = (float*)(BfragH + (size_t)NPROB * NT2 * 64 * 8); // [32][VH]
    float*          objm   = rowm + (size_t)NPROB * VH;                // [32][2048]
    float*          acc    = objm + (size_t)NPROB * 2048;              // 16 f

    prep_kernel<<<1120, 256, 0, stream>>>(hv, ov, ghv, gov, BfragO, BfragH,
                                          (unsigned int*)acc);

    mindist_mfma<<<NBLK1 + NBLK2, 256, 0, stream>>>(hv, ov, ghv, gov,
                                                    BfragO, BfragH, rowm, objm);

    reduce_kernel<<<NBLKR, 256, 0, stream>>>(rowm, objm, acc);

    finalize_kernel<<<1, 1, 0, stream>>>(acc, (float*)d_out);
}

// Round 11
// 134.710 us; speedup vs baseline: 1.0355x; 1.0355x over previous
//
#include <hip/hip_runtime.h>
#include <math.h>

// InterContactLoss on MI355X — round 11: XCD-swizzled blocks + 4-deep prefetch.
//
// r10 evidence: fence fix confirmed (reduce/finalize gone from top-5), but
// FETCH 9.6->37.7MB: pass2 panels (221KB/prob) re-fetched by ~8 XCDs (blocks
// round-robin across XCDs; per-XCD L2s private) -> latency-bound loads
// (VALUBusy 37%, occup 27%, 2-pair prefetch). Fixes:
//  - bijective XCD swizzle: prob = (blockIdx&7) + 8*(y/RBLK) -> each XCD owns
//    4 probs' panels (1.14MB < 4MB L2); pass1+pass2 same-prob same-XCD.
//  - 4-deep pair prefetch ring (named bufs bA..bD, no runtime indexing):
//    loads issue 3-4 stages (~150-250cy) before the consuming MFMA.
// MFMA/RED physical-VGPR-bank chain unchanged (absmax 0.0 for 3 rounds).

#define BT 16
#define VH 6890
#define VO 2048
#define NH (BT * VH)    // 110240
#define NO (BT * VO)    // 32768
#define RBLK1 54        // pass1 row-blocks/prob: ceil(6890/128)
#define RBLK2 16        // pass2 row-blocks/prob: 2048/128
#define NT1 64          // pass1 col tiles (2048/32)  -> 32 pairs
#define NT2 216         // pass2 col tiles (6912/32)  -> 108 pairs
#define NPROB 32        // 16 bt x {pred,gt}
#define NBLK1 (NPROB * RBLK1)   // 1728 (divisible by 8)
#define NBLK2 (NPROB * RBLK2)   // 512  (divisible by 8)

typedef __attribute__((ext_vector_type(8))) short          short8;
typedef __attribute__((ext_vector_type(8))) unsigned short ushort8;

__device__ __forceinline__ unsigned short bf16_rne(float f) {
    const unsigned int u = __float_as_uint(f);
    return (unsigned short)((u + 0x7FFFu + ((u >> 16) & 1u)) >> 16);
}
__device__ __forceinline__ float bf16_tof(unsigned short h) {
    return __uint_as_float(((unsigned int)h) << 16);
}

#define CLOB_B0 "v40","v41","v42","v43","v44","v45","v46","v47", \
                "v48","v49","v50","v51","v52","v53","v54","v55", \
                "v56","v57","v58","v59","v60","v61","v62","v63", \
                "v64","v65","v66","v67","v68","v69","v70","v71"
#define CLOB_B1 "v72","v73","v74","v75","v76","v77","v78","v79", \
                "v80","v81","v82","v83","v84","v85","v86","v87", \
                "v88","v89","v90","v91","v92","v93","v94","v95", \
                "v96","v97","v98","v99","v100","v101","v102","v103"

#define MFMA_B0(b0, b1) \
    asm volatile("v_mfma_f32_32x32x16_bf16 v[40:55], %0, %1, 0\n\t" \
                 "v_mfma_f32_32x32x16_bf16 v[56:71], %0, %2, 0" \
                 :: "v"(a8), "v"(b0), "v"(b1) : CLOB_B0)
#define MFMA_B1(b0, b1) \
    asm volatile("v_mfma_f32_32x32x16_bf16 v[72:87], %0, %1, 0\n\t" \
                 "v_mfma_f32_32x32x16_bf16 v[88:103], %0, %2, 0" \
                 :: "v"(a8), "v"(b0), "v"(b1) : CLOB_B1)

#define RED_B0() \
    asm volatile( \
        "v_min3_f32 %0, %0, v40, v56\n\t"  "v_min3_f32 %1, %1, v41, v57\n\t" \
        "v_min3_f32 %2, %2, v42, v58\n\t"  "v_min3_f32 %3, %3, v43, v59\n\t" \
        "v_min3_f32 %4, %4, v44, v60\n\t"  "v_min3_f32 %5, %5, v45, v61\n\t" \
        "v_min3_f32 %6, %6, v46, v62\n\t"  "v_min3_f32 %7, %7, v47, v63\n\t" \
        "v_min3_f32 %8, %8, v48, v64\n\t"  "v_min3_f32 %9, %9, v49, v65\n\t" \
        "v_min3_f32 %10, %10, v50, v66\n\t" "v_min3_f32 %11, %11, v51, v67\n\t" \
        "v_min3_f32 %12, %12, v52, v68\n\t" "v_min3_f32 %13, %13, v53, v69\n\t" \
        "v_min3_f32 %14, %14, v54, v70\n\t" "v_min3_f32 %15, %15, v55, v71" \
        : "+v"(rm[0]), "+v"(rm[1]), "+v"(rm[2]),  "+v"(rm[3]), \
          "+v"(rm[4]), "+v"(rm[5]), "+v"(rm[6]),  "+v"(rm[7]), \
          "+v"(rm[8]), "+v"(rm[9]), "+v"(rm[10]), "+v"(rm[11]), \
          "+v"(rm[12]),"+v"(rm[13]),"+v"(rm[14]), "+v"(rm[15]))
#define RED_B1() \
    asm volatile( \
        "v_min3_f32 %0, %0, v72, v88\n\t"  "v_min3_f32 %1, %1, v73, v89\n\t" \
        "v_min3_f32 %2, %2, v74, v90\n\t"  "v_min3_f32 %3, %3, v75, v91\n\t" \
        "v_min3_f32 %4, %4, v76, v92\n\t"  "v_min3_f32 %5, %5, v77, v93\n\t" \
        "v_min3_f32 %6, %6, v78, v94\n\t"  "v_min3_f32 %7, %7, v79, v95\n\t" \
        "v_min3_f32 %8, %8, v80, v96\n\t"  "v_min3_f32 %9, %9, v81, v97\n\t" \
        "v_min3_f32 %10, %10, v82, v98\n\t" "v_min3_f32 %11, %11, v83, v99\n\t" \
        "v_min3_f32 %12, %12, v84, v100\n\t" "v_min3_f32 %13, %13, v85, v101\n\t" \
        "v_min3_f32 %14, %14, v86, v102\n\t" "v_min3_f32 %15, %15, v87, v103" \
        : "+v"(rm[0]), "+v"(rm[1]), "+v"(rm[2]),  "+v"(rm[3]), \
          "+v"(rm[4]), "+v"(rm[5]), "+v"(rm[6]),  "+v"(rm[7]), \
          "+v"(rm[8]), "+v"(rm[9]), "+v"(rm[10]), "+v"(rm[11]), \
          "+v"(rm[12]),"+v"(rm[13]),"+v"(rm[14]), "+v"(rm[15]))

// ---- prep: object B-frags (64 tiles) + human B-frags (216 tiles) + acc zero ----
__global__ __launch_bounds__(256)
void prep_kernel(const float* __restrict__ hv,  const float* __restrict__ ov,
                 const float* __restrict__ ghv, const float* __restrict__ gov,
                 unsigned short* __restrict__ BfragO, unsigned short* __restrict__ BfragH,
                 unsigned int* __restrict__ acc)
{
    const int t = blockIdx.x * 256 + threadIdx.x;   // 286720 total
    if (t < 16) acc[t] = 0u;

    const unsigned short one = 0x3F80;
    if (t < 65536) {                                // object frags: [pg][bt][col<2048]
        const int col = t & 2047;
        const int bt  = (t >> 11) & 15;
        const int pg  = t >> 15;
        const float* B = (pg ? gov : ov) + ((size_t)bt * VO + col) * 3;
        const float bx = B[0], by = B[1], bz = B[2];
        const float m2x = -2.f * bx, m2y = -2.f * by, m2z = -2.f * bz;
        const float bb  = fmaf(bx, bx, fmaf(by, by, bz * bz));
        const unsigned short hx = bf16_rne(m2x), hy = bf16_rne(m2y), hz = bf16_rne(m2z);
        const unsigned short lx = bf16_rne(m2x - bf16_tof(hx));
        const unsigned short ly = bf16_rne(m2y - bf16_tof(hy));
        const unsigned short lz = bf16_rne(m2z - bf16_tof(hz));
        const unsigned short bh = bf16_rne(bb);
        const unsigned short bl = bf16_rne(bb - bf16_tof(bh));
        const int prob = pg * 16 + bt;
        unsigned short* d0 = BfragO +
            ((size_t)((prob * NT1 + (col >> 5)) * 64 + (col & 31))) * 8;
        const ushort8 w0 = {hx, hy, hz, hx, hy, hz, one, one};   // k0..7
        const ushort8 w1 = {lx, ly, lz, lx, ly, lz, bh, bl};     // k8..15
        *(ushort8*)d0         = w0;
        *(ushort8*)(d0 + 256) = w1;
    } else {                                        // human frags: [prob][col<6912]
        const int t2   = t - 65536;                 // 221184 = 32 * 6912
        const int col  = t2 % 6912;
        const int prob = t2 / 6912;
        const int pg = prob >> 4, bt = prob & 15;
        ushort8 w0, w1;
        if (col < VH) {
            const float* B = (pg ? ghv : hv) + ((size_t)bt * VH + col) * 3;
            const float bx = B[0], by = B[1], bz = B[2];
            const float m2x = -2.f * bx, m2y = -2.f * by, m2z = -2.f * bz;
            const float bb  = fmaf(bx, bx, fmaf(by, by, bz * bz));
            const unsigned short hx = bf16_rne(m2x), hy = bf16_rne(m2y), hz = bf16_rne(m2z);
            const unsigned short lx = bf16_rne(m2x - bf16_tof(hx));
            const unsigned short ly = bf16_rne(m2y - bf16_tof(hy));
            const unsigned short lz = bf16_rne(m2z - bf16_tof(hz));
            const unsigned short bh = bf16_rne(bb);
            const unsigned short bl = bf16_rne(bb - bf16_tof(bh));
            w0 = (ushort8){hx, hy, hz, hx, hy, hz, one, one};
            w1 = (ushort8){lx, ly, lz, lx, ly, lz, bh, bl};
        } else {
            // pad col: b=0, bb=1e36 -> d2 = aa + 1e36, never the min
            const unsigned short big = bf16_rne(1.0e36f);
            w0 = (ushort8){0, 0, 0, 0, 0, 0, one, one};
            w1 = (ushort8){0, 0, 0, 0, 0, 0, big, 0};
        }
        unsigned short* d0 = BfragH +
            ((size_t)((prob * NT2 + (col >> 5)) * 64 + (col & 31))) * 8;
        *(ushort8*)d0         = w0;
        *(ushort8*)(d0 + 256) = w1;
    }
}

// ---- mindist: 2240 blocks, XCD-swizzled; pass1 human rows, pass2 object rows ----
__global__ __launch_bounds__(256)
void mindist_mfma(const float* __restrict__ hv,  const float* __restrict__ ov,
                  const float* __restrict__ ghv, const float* __restrict__ gov,
                  const unsigned short* __restrict__ BfragO,
                  const unsigned short* __restrict__ BfragH,
                  float* __restrict__ rowm,      // [prob][VH]   human-side min d2
                  float* __restrict__ objm)      // [prob][2048] object-side min d2
{
    const int tid  = threadIdx.x;
    const int lane = tid & 63;
    const int wave = tid >> 6;
    const int b    = blockIdx.x;

    const float* A;
    const short8* bls;
    float* out;
    int pairs, nA, row0;

    // XCD swizzle: prob = (b&7) + 8*(y/RBLK) -> all blocks of a prob share an
    // XCD (blocks dispatch round-robin across the 8 XCDs); bijective.
    if (b < NBLK1) {
        const int x = b & 7, y = b >> 3;            // y in [0,216)
        const int q = y / RBLK1, rblk = y - q * RBLK1;
        const int prob = x + 8 * q;
        const int pg = prob >> 4, bt = prob & 15;
        A    = (pg ? ghv : hv) + (size_t)bt * VH * 3;
        bls  = (const short8*)BfragO + (size_t)prob * (NT1 * 64);
        out  = rowm + (size_t)prob * VH;
        pairs = NT1 / 2; nA = VH; row0 = rblk * 128 + wave * 32;
    } else {
        const int b2 = b - NBLK1;                   // [0,512)
        const int x = b2 & 7, y = b2 >> 3;          // y in [0,64)
        const int q = y >> 4, rblk = y & 15;
        const int prob = x + 8 * q;
        const int pg = prob >> 4, bt = prob & 15;
        A    = (pg ? gov : ov) + (size_t)bt * VO * 3;
        bls  = (const short8*)BfragH + (size_t)prob * (NT2 * 64);
        out  = objm + (size_t)prob * 2048;
        pairs = NT2 / 2; nA = VO; row0 = rblk * 128 + wave * 32;
    }

    // ---- A fragment: 32 rows/wave, split-bf16; pad rows -> (1e4,0,0) ----
    const int r = row0 + (lane & 31);
    float x, y, z;
    if (r < nA) { x = A[3*r]; y = A[3*r+1]; z = A[3*r+2]; }
    else        { x = 1.0e4f; y = 0.f;      z = 0.f; }
    const float aa = fmaf(x, x, fmaf(y, y, z * z));
    const unsigned short ahx = bf16_rne(x), ahy = bf16_rne(y), ahz = bf16_rne(z);
    const unsigned short alx = bf16_rne(x - bf16_tof(ahx));
    const unsigned short aly = bf16_rne(y - bf16_tof(ahy));
    const unsigned short alz = bf16_rne(z - bf16_tof(ahz));
    const unsigned short aah = bf16_rne(aa);
    const unsigned short aal = bf16_rne(aa - bf16_tof(aah));
    const int g = lane >> 5;
    ushort8 a8u;
    a8u[0] = ahx; a8u[1] = ahy; a8u[2] = ahz;
    a8u[3] = alx; a8u[4] = aly; a8u[5] = alz;
    a8u[6] = g ? (unsigned short)0x3F80 : aah;
    a8u[7] = g ? (unsigned short)0x3F80 : aal;
    const short8 a8 = (short8)a8u;

#define LDT(jt) bls[(jt) * 64 + lane]
    float rm[16];
#pragma unroll
    for (int i = 0; i < 16; ++i) rm[i] = 3.0e38f;

    // 4-deep pair prefetch ring (pairs: P = 32 or 108, both %4 == 0).
    // Steady state: loads for pair p+4..p+7 issue 3-4 stages before use.
    short8 bAl = LDT(0), bAh = LDT(1);    // pair0
    short8 bBl = LDT(2), bBh = LDT(3);    // pair1
    short8 bCl = LDT(4), bCh = LDT(5);    // pair2
    short8 bDl = LDT(6), bDh = LDT(7);    // pair3
    MFMA_B0(bAl, bAh);                    // pair0 -> bank0 (even pair -> B0)

    for (int p = 0; p + 8 <= pairs; p += 4) {
        bAl = LDT(2*(p+4)); bAh = LDT(2*(p+4)+1);
        MFMA_B1(bBl, bBh);  RED_B0();     // pair p+1; reduce pair p
        bBl = LDT(2*(p+5)); bBh = LDT(2*(p+5)+1);
        MFMA_B0(bCl, bCh);  RED_B1();     // pair p+2; reduce p+1
        bCl = LDT(2*(p+6)); bCh = LDT(2*(p+6)+1);
        MFMA_B1(bDl, bDh);  RED_B0();     // pair p+3; reduce p+2
        bDl = LDT(2*(p+7)); bDh = LDT(2*(p+7)+1);
        MFMA_B0(bAl, bAh);  RED_B1();     // pair p+4; reduce p+3
    }
    // buffers hold pairs P-3 (B), P-2 (C), P-1 (D); MFMA(P-4) in flight on B0
    MFMA_B1(bBl, bBh);  RED_B0();         // pair P-3; reduce P-4
    MFMA_B0(bCl, bCh);  RED_B1();         // pair P-2; reduce P-3
    MFMA_B1(bDl, bDh);  RED_B0();         // pair P-1; reduce P-2
    asm volatile("s_nop 7\n\ts_nop 7");
    RED_B1();                             // reduce P-1
#undef LDT

    // ---- row-min butterfly across the 32 col-lanes, then direct store ----
#pragma unroll
    for (int i = 0; i < 16; ++i) {
        float v = rm[i];
        v = fminf(v, __shfl_xor(v, 1));
        v = fminf(v, __shfl_xor(v, 2));
        v = fminf(v, __shfl_xor(v, 4));
        v = fminf(v, __shfl_xor(v, 8));
        v = fminf(v, __shfl_xor(v, 16));
        rm[i] = v;
    }
    if ((lane & 31) == 0) {               // lanes 0 and 32 hold 16 rows each
#pragma unroll
        for (int i = 0; i < 16; ++i) {
            const int rr = row0 + (i & 3) + 8 * (i >> 2) + 4 * g;
            if (rr < nA) out[rr] = fmaxf(rm[i], 0.f);
        }
    }
}

// ---- reduce: per-element loss -> block sums -> device atomicAdd (NO fence) ----
#define NBLK_H 431   // ceil(110240/256)
#define NBLK_O 128   // 32768/256
#define NBLKR  (NBLK_H + NBLK_O)

__global__ __launch_bounds__(256)
void reduce_kernel(const float* __restrict__ rowm, const float* __restrict__ objm,
                   float* __restrict__ acc)
{
    const int b = blockIdx.x;
    float p2 = 3.0e38f, g2 = 3.0e38f;
    float* a4;
    bool valid;

    if (b < NBLK_H) {
        a4 = acc;
        const int i = b * 256 + threadIdx.x;
        valid = (i < NH);
        if (valid) {
            const int bt = i / VH;
            const int r  = i - bt * VH;
            p2 = rowm[(size_t)bt * VH + r];
            g2 = rowm[(size_t)(16 + bt) * VH + r];
        }
    } else {
        a4 = acc + 4;
        const int i = (b - NBLK_H) * 256 + threadIdx.x;
        valid = true;
        const int bt = i >> 11;
        const int j  = i & 2047;
        p2 = objm[(size_t)bt * 2048 + j];
        g2 = objm[(size_t)(16 + bt) * 2048 + j];
    }

    float t = 0.f, sp = 0.f, sn = 0.f, sh = 0.f;
    if (valid) {
        const float d  = sqrtf(p2);
        const float dg = sqrtf(g2);
        const float tt = (dg < 0.2f) ? 1.f : 0.f;

        const float z = (0.2f - d) * 100.0f;           // (DIST_THR - d)/ALPHA
        float p = 1.0f / (1.0f + expf(-z));
        p = fminf(fmaxf(p, 1e-6f), 1.0f - 1e-6f);
        const float bce = (tt > 0.5f) ? -logf(p) : -logf(1.0f - p);

        const float over = fmaxf(d - 0.1f, 0.0f);      // d - CONTACT_TGT
        const float hub  = (over < 0.01f) ? (0.5f * over * over) / 0.01f
                                          : (over - 0.5f * 0.01f);
        t  = tt;
        sp = tt * bce;
        sn = (1.0f - tt) * bce;
        sh = tt * hub;
    }
    for (int off = 32; off > 0; off >>= 1) {
        t  += __shfl_down(t,  off);
        sp += __shfl_down(sp, off);
        sn += __shfl_down(sn, off);
        sh += __shfl_down(sh, off);
    }
    __shared__ float wsum[4][4];
    const int wid = threadIdx.x >> 6, lane = threadIdx.x & 63;
    if (lane == 0) {
        wsum[wid][0] = t; wsum[wid][1] = sp; wsum[wid][2] = sn; wsum[wid][3] = sh;
    }
    __syncthreads();
    if (threadIdx.x == 0) {
        float s0 = 0, s1 = 0, s2 = 0, s3 = 0;
        for (int w = 0; w < 4; ++w) {
            s0 += wsum[w][0]; s1 += wsum[w][1]; s2 += wsum[w][2]; s3 += wsum[w][3];
        }
        atomicAdd(&a4[0], s0);
        atomicAdd(&a4[1], s1);
        atomicAdd(&a4[2], s2);
        atomicAdd(&a4[3], s3);
    }
}

// ---- finalize: one thread; previous kernel's atomics visible at boundary ----
__global__ void finalize_kernel(const float* __restrict__ acc, float* __restrict__ outp)
{
    const float Ph = acc[0], SpH = acc[1], SnH = acc[2], ShH = acc[3];
    const float Po = acc[4], SpO = acc[5], SnO = acc[6], ShO = acc[7];
    const float Nh = (float)NH, No = (float)NO;

    const float pwH = ((Nh - Ph) + 1e-6f) / (Ph + 1e-6f);
    const float pwO = ((No - Po) + 1e-6f) / (Po + 1e-6f);
    const float bceH = (pwH * SpH + SnH) / Nh;
    const float bceO = (pwO * SpO + SnO) / No;
    const float Lbce = 0.5f * (bceH + bceO);

    const float LdH = (Ph > 0.f) ? ShH / fmaxf(Ph, 1.f) : 0.f;
    const float LdO = (Po > 0.f) ? ShO / fmaxf(Po, 1.f) : 0.f;

    outp[0] = 0.5f * Lbce + (LdH + LdO);
}

extern "C" void kernel_launch(void* const* d_in, const int* in_sizes, int n_in,
                              void* d_out, int out_size, void* d_ws, size_t ws_size,
                              hipStream_t stream)
{
    const float* hv  = (const float*)d_in[0];
    const float* ov  = (const float*)d_in[1];
    const float* ghv = (const float*)d_in[2];
    const float* gov = (const float*)d_in[3];

    unsigned short* BfragO = (unsigned short*)d_ws;                    // 32*64*64*8  = 2MB
    unsigned short* BfragH = BfragO + (size_t)NPROB * NT1 * 64 * 8;    // 32*216*64*8 ~ 6.75MB
    float*          rowm   = (float*)(BfragH + (size_t)NPROB * NT2 * 64 * 8); // [32][VH]
    float*          objm   = rowm + (size_t)NPROB * VH;                // [32][2048]
    float*          acc    = objm + (size_t)NPROB * 2048;              // 16 f

    prep_kernel<<<1120, 256, 0, stream>>>(hv, ov, ghv, gov, BfragO, BfragH,
                                          (unsigned int*)acc);

    mindist_mfma<<<NBLK1 + NBLK2, 256, 0, stream>>>(hv, ov, ghv, gov,
                                                    BfragO, BfragH, rowm, objm);

    reduce_kernel<<<NBLKR, 256, 0, stream>>>(rowm, objm, acc);

    finalize_kernel<<<1, 1, 0, stream>>>(acc, (float*)d_out);
}